// Round 5
// baseline (251.288 us; speedup 1.0000x reference)
//
#include <hip/hip_runtime.h>
#include <math.h>

constexpr int D = 128;       // in_channels
constexpr int B = 512;       // batch_size (graphs)
constexpr int STEPS = 3;
constexpr int NW_IH = 3 * D * 2 * D;   // 98304 elems, Wih [3D][2D]
constexpr int NW_HH = 3 * D * D;       // 49152 elems, Whh [3D][D]

__device__ __forceinline__ float sigmoidf_(float x) { return 1.f / (1.f + __expf(-x)); }
// bf16 pair unpack from a uint: low halfword / high halfword -> float (exact)
__device__ __forceinline__ float bflo(unsigned int u) { return __uint_as_float(u << 16); }
__device__ __forceinline__ float bfhi(unsigned int u) { return __uint_as_float(u & 0xffff0000u); }
__device__ __forceinline__ unsigned short f2bf_rn(float f) {
    unsigned int u = __float_as_uint(f);
    u += 0x7fffu + ((u >> 16) & 1u);    // round-to-nearest-even
    return (unsigned short)(u >> 16);
}

// ---------------------------------------------------------------------------
// K0 (prep): weights fp32 -> bf16 (RN), plus segment bounds via binary search
// on sorted batch[] (seg[g] = first index with batch[i] >= g).
// ---------------------------------------------------------------------------
__global__ __launch_bounds__(256) void k_prep(const float* __restrict__ Wih,
        const float* __restrict__ Whh, const int* __restrict__ batch, int n,
        unsigned short* __restrict__ wih_bf, unsigned short* __restrict__ whh_bf,
        int* __restrict__ seg) {
    int i = blockIdx.x * blockDim.x + threadIdx.x;
    if (i < NW_IH) wih_bf[i] = f2bf_rn(Wih[i]);
    else if (i < NW_IH + NW_HH) whh_bf[i - NW_IH] = f2bf_rn(Whh[i - NW_IH]);
    if (i <= B) {
        int lo = 0, hi = n;
        while (lo < hi) { int mid = (lo + hi) >> 1; if (batch[mid] < i) lo = mid + 1; else hi = mid; }
        seg[i] = lo;
    }
}

// ---------------------------------------------------------------------------
// K1 (fused Set2Set): one block per graph, 1024 threads, all 3 steps inside.
// State (h, q_star) in LDS; no global intermediates (recurrence is per-graph).
//   GRU:  threads 0..383 compute gate rows, bf16 weights, 4 parallel fma
//         accumulator chains per thread (chain depth 768 -> ~64/acc).
//   Attn: flash-style single pass; each half-wave processes a CHUNK of 4
//         consecutive nodes per iteration (4 independent loads / dots /
//         shuffle-reduces, one rescale per chunk) for ~4x ILP.
// __launch_bounds__(1024,8): VGPR<=64 -> 2 blocks/CU = 32 waves/CU.
// ---------------------------------------------------------------------------
__global__ __launch_bounds__(1024, 8) void k_set2set(
        const float* __restrict__ x,
        const unsigned short* __restrict__ wih_bf,
        const unsigned short* __restrict__ whh_bf,
        const float* __restrict__ bih, const float* __restrict__ bhh,
        const int* __restrict__ seg, float* __restrict__ out) {
    __shared__ float s_q[2 * D];          // q_star for this graph: [q | r]
    __shared__ float s_h[D];
    __shared__ float s_gi[3 * D], s_gh[3 * D];
    __shared__ float sm[32], sl[32];
    __shared__ float s_M, s_inv;
    __shared__ float rpart[16][D];        // 8 KB

    const int b = blockIdx.x;
    const int tid = threadIdx.x;
    const int start = seg[b], end = seg[b + 1];
    const int lane32 = tid & 31;
    const int hw = tid >> 5;              // half-wave id 0..31

    if (tid < 2 * D) s_q[tid] = 0.f;
    if (tid < D) s_h[tid] = 0.f;
    __syncthreads();

    for (int step = 0; step < STEPS; ++step) {
        // ---- GRU gate rows (384 threads, 4 parallel acc chains each) ----
        if (tid < 3 * D) {
            const int t = tid;
            float g0 = bih[t], g1 = 0.f, g2 = 0.f, g3 = 0.f;
            const uint4* wr = (const uint4*)(wih_bf + (size_t)t * (2 * D));
#pragma unroll 4
            for (int c = 0; c < (2 * D) / 8; ++c) {
                uint4 w = wr[c];
                const float* q = &s_q[c * 8];
                g0 = fmaf(bflo(w.x), q[0], g0); g0 = fmaf(bfhi(w.x), q[1], g0);
                g1 = fmaf(bflo(w.y), q[2], g1); g1 = fmaf(bfhi(w.y), q[3], g1);
                g2 = fmaf(bflo(w.z), q[4], g2); g2 = fmaf(bfhi(w.z), q[5], g2);
                g3 = fmaf(bflo(w.w), q[6], g3); g3 = fmaf(bfhi(w.w), q[7], g3);
            }
            s_gi[t] = (g0 + g1) + (g2 + g3);
            float h0 = bhh[t], h1 = 0.f, h2 = 0.f, h3 = 0.f;
            const uint4* vr = (const uint4*)(whh_bf + (size_t)t * D);
#pragma unroll 4
            for (int c = 0; c < D / 8; ++c) {
                uint4 w = vr[c];
                const float* hh = &s_h[c * 8];
                h0 = fmaf(bflo(w.x), hh[0], h0); h0 = fmaf(bfhi(w.x), hh[1], h0);
                h1 = fmaf(bflo(w.y), hh[2], h1); h1 = fmaf(bfhi(w.y), hh[3], h1);
                h2 = fmaf(bflo(w.z), hh[4], h2); h2 = fmaf(bfhi(w.z), hh[5], h2);
                h3 = fmaf(bflo(w.w), hh[6], h3); h3 = fmaf(bfhi(w.w), hh[7], h3);
            }
            s_gh[t] = (h0 + h1) + (h2 + h3);
        }
        __syncthreads();
        // ---- GRU epilogue ----
        if (tid < D) {
            const int t = tid;
            float r  = sigmoidf_(s_gi[t] + s_gh[t]);
            float z  = sigmoidf_(s_gi[D + t] + s_gh[D + t]);
            float nn = tanhf(s_gi[2 * D + t] + r * s_gh[2 * D + t]);
            float hn = (1.f - z) * nn + z * s_h[t];
            s_h[t] = hn;
            s_q[t] = hn;                  // q part of q_star
        }
        __syncthreads();

        // ---- flash attention, 4-node chunks per half-wave ----
        const float4 qf = *(const float4*)&s_h[lane32 * 4];
        float m_run = -INFINITY, l_run = 0.f;
        float4 acc = {0.f, 0.f, 0.f, 0.f};
        for (int base = start + hw * 4; base < end; base += 32 * 4) {
            // 4 unconditional clamped loads (contiguous 2 KB per half-wave)
            float4 xv0, xv1, xv2, xv3;
            {
                int n0 = base;
                int n1 = (base + 1 < end) ? base + 1 : end - 1;
                int n2 = (base + 2 < end) ? base + 2 : end - 1;
                int n3 = (base + 3 < end) ? base + 3 : end - 1;
                xv0 = ((const float4*)(x + (size_t)n0 * D))[lane32];
                xv1 = ((const float4*)(x + (size_t)n1 * D))[lane32];
                xv2 = ((const float4*)(x + (size_t)n2 * D))[lane32];
                xv3 = ((const float4*)(x + (size_t)n3 * D))[lane32];
            }
            float p0 = fmaf(xv0.x, qf.x, fmaf(xv0.y, qf.y, fmaf(xv0.z, qf.z, xv0.w * qf.w)));
            float p1 = fmaf(xv1.x, qf.x, fmaf(xv1.y, qf.y, fmaf(xv1.z, qf.z, xv1.w * qf.w)));
            float p2 = fmaf(xv2.x, qf.x, fmaf(xv2.y, qf.y, fmaf(xv2.z, qf.z, xv2.w * qf.w)));
            float p3 = fmaf(xv3.x, qf.x, fmaf(xv3.y, qf.y, fmaf(xv3.z, qf.z, xv3.w * qf.w)));
#pragma unroll
            for (int s = 16; s >= 1; s >>= 1) {
                p0 += __shfl_xor(p0, s, 64);
                p1 += __shfl_xor(p1, s, 64);
                p2 += __shfl_xor(p2, s, 64);
                p3 += __shfl_xor(p3, s, 64);
            }
            if (base + 1 >= end) p1 = -INFINITY;
            if (base + 2 >= end) p2 = -INFINITY;
            if (base + 3 >= end) p3 = -INFINITY;

            float cm = fmaxf(fmaxf(p0, p1), fmaxf(p2, p3));
            float nm = fmaxf(m_run, cm);
            float scale = __expf(m_run - nm);   // 0 on first chunk
            float a0 = __expf(p0 - nm);
            float a1 = __expf(p1 - nm);
            float a2 = __expf(p2 - nm);
            float a3 = __expf(p3 - nm);
            l_run = fmaf(l_run, scale, (a0 + a1) + (a2 + a3));
            acc.x = fmaf(acc.x, scale, fmaf(a0, xv0.x, fmaf(a1, xv1.x, fmaf(a2, xv2.x, a3 * xv3.x))));
            acc.y = fmaf(acc.y, scale, fmaf(a0, xv0.y, fmaf(a1, xv1.y, fmaf(a2, xv2.y, a3 * xv3.y))));
            acc.z = fmaf(acc.z, scale, fmaf(a0, xv0.z, fmaf(a1, xv1.z, fmaf(a2, xv2.z, a3 * xv3.z))));
            acc.w = fmaf(acc.w, scale, fmaf(a0, xv0.w, fmaf(a1, xv1.w, fmaf(a2, xv2.w, a3 * xv3.w))));
            m_run = nm;
        }
        if (lane32 == 0) { sm[hw] = m_run; sl[hw] = l_run; }
        __syncthreads();
        if (tid == 0) {
            float M = -INFINITY;
            for (int i = 0; i < 32; ++i) M = fmaxf(M, sm[i]);
            float L = 0.f;
            for (int i = 0; i < 32; ++i)
                L += (sm[i] == -INFINITY) ? 0.f : sl[i] * __expf(sm[i] - M);
            s_M = M;
            s_inv = 1.f / (L + 1e-16f);
        }
        __syncthreads();
        // rescale to global max; empty half-wave / empty graph -> exactly 0
        const float fac = (m_run == -INFINITY) ? 0.f : __expf(m_run - s_M);
        acc.x *= fac; acc.y *= fac; acc.z *= fac; acc.w *= fac;
        // fold upper half-wave onto lower within each 64-lane wave
        acc.x += __shfl_down(acc.x, 32, 64);
        acc.y += __shfl_down(acc.y, 32, 64);
        acc.z += __shfl_down(acc.z, 32, 64);
        acc.w += __shfl_down(acc.w, 32, 64);
        const int wave = tid >> 6;        // 0..15
        const int lane64 = tid & 63;
        if (lane64 < 32) ((float4*)rpart[wave])[lane64] = acc;
        __syncthreads();
        if (tid < D) {
            float v = 0.f;
#pragma unroll
            for (int w = 0; w < 16; ++w) v += rpart[w][tid];
            s_q[D + tid] = v * s_inv;     // r part of q_star
        }
        __syncthreads();                  // s_q complete for next GRU / output
    }

    // ---- write q_star row (s_q is exactly [q | r]) ----
    if (tid < 2 * D) out[(size_t)b * (2 * D) + tid] = s_q[tid];
}

// ---------------------------------------------------------------------------
extern "C" void kernel_launch(void* const* d_in, const int* in_sizes, int n_in,
                              void* d_out, int out_size, void* d_ws, size_t ws_size,
                              hipStream_t stream) {
    const float* x    = (const float*)d_in[0];
    const int*   batch= (const int*)d_in[1];
    // d_in[2] = batch_size scalar (fixed at B=512 compile time)
    const float* Wih  = (const float*)d_in[3];
    const float* Whh  = (const float*)d_in[4];
    const float* bih  = (const float*)d_in[5];
    const float* bhh  = (const float*)d_in[6];
    const int n = in_sizes[0] / D;        // 200000

    // workspace: seg (4 KB pad) | wih_bf (192 KB) | whh_bf (96 KB)
    char* ws = (char*)d_ws;
    int* seg = (int*)ws;
    unsigned short* wih_bf = (unsigned short*)(ws + 4096);
    unsigned short* whh_bf = (unsigned short*)(ws + 4096 + (size_t)NW_IH * 2);

    const int total = NW_IH + NW_HH;      // 147456 >= B+1, covers seg too
    k_prep<<<(total + 255) / 256, 256, 0, stream>>>(Wih, Whh, batch, n, wih_bf, whh_bf, seg);
    k_set2set<<<B, 1024, 0, stream>>>(x, wih_bf, whh_bf, bih, bhh, seg, (float*)d_out);
}